// Round 1
// baseline (301.382 us; speedup 1.0000x reference)
//
#include <hip/hip_runtime.h>
#include <stdint.h>

static constexpr int TOPK   = 8;
static constexpr int NGROUP = 8;
static constexpr int TOPKG  = 4;
static constexpr int NEXP   = 256;
static constexpr float RSF  = 2.5f;

// Monotonic float -> uint32 transform (total order, matches float compare on non-NaN)
__device__ __forceinline__ uint32_t f2sort(float f) {
    uint32_t u = __float_as_uint(f);
    return u ^ ((u & 0x80000000u) ? 0xFFFFFFFFu : 0x80000000u);
}

__device__ __forceinline__ uint64_t umax64(uint64_t a, uint64_t b) { return a > b ? a : b; }

__global__ __launch_bounds__(256) void router_kernel(
    const float* __restrict__ logits,   // [T, 256]
    const float* __restrict__ bias,     // [256]
    float* __restrict__ out_w,          // [T, 8]
    float* __restrict__ out_id,         // [T, 8] (ids as float values)
    int T)
{
    const int lane  = threadIdx.x & 63;
    const int token = blockIdx.x * (blockDim.x >> 6) + (threadIdx.x >> 6);
    if (token >= T) return;

    // lane i owns experts 4i..4i+3 (all within one 32-expert group since 4|32)
    float4 v = ((const float4*)(logits + (size_t)token * NEXP))[lane];
    float4 b = ((const float4*)bias)[lane];

    const float s0 = v.x + b.x;
    const float s1 = v.y + b.y;
    const float s2 = v.z + b.z;
    const float s3 = v.w + b.w;

    // ---- group score: sum of top-2 biased scores within each 8-lane (32-expert) group ----
    // local sorted top-2 of the lane's 4 values
    float hi01 = fmaxf(s0, s1), lo01 = fminf(s0, s1);
    float hi23 = fmaxf(s2, s3), lo23 = fminf(s2, s3);
    float m1 = fmaxf(hi01, hi23);
    float m2 = fmaxf(fminf(hi01, hi23), fmaxf(lo01, lo23));
    // merge sorted-2 lists across the 8-lane subgroup (xor 1,2,4 stays in-group)
    #pragma unroll
    for (int mask = 1; mask <= 4; mask <<= 1) {
        float o1 = __shfl_xor(m1, mask, 64);
        float o2 = __shfl_xor(m2, mask, 64);
        float n1 = fmaxf(m1, o1);
        float n2 = fmaxf(fminf(m1, o1), fmaxf(m2, o2));
        m1 = n1; m2 = n2;
    }
    const float gscore = m1 + m2;   // identical across the 8 lanes of the group

    // ---- select top-4 groups; tie -> lower group index (jax.lax.top_k semantics) ----
    const int g = lane >> 3;
    int rank = 0;
    #pragma unroll
    for (int j = 0; j < NGROUP; ++j) {
        float gj = __shfl(gscore, j << 3, 64);
        rank += (gj > gscore) || (gj == gscore && j < g);
    }
    const bool sel = (rank < TOPKG);

    // ---- sortable 64-bit keys: [sortable(value) : (255 - expert_idx)] ----
    // masked (non-selected group) -> key 0, below any finite value's key
    const uint32_t e0 = (uint32_t)(lane * 4);
    uint64_t k0 = sel ? (((uint64_t)f2sort(s0) << 32) | (255u - e0))       : 0ull;
    uint64_t k1 = sel ? (((uint64_t)f2sort(s1) << 32) | (255u - (e0 + 1))) : 0ull;
    uint64_t k2 = sel ? (((uint64_t)f2sort(s2) << 32) | (255u - (e0 + 2))) : 0ull;
    uint64_t k3 = sel ? (((uint64_t)f2sort(s3) << 32) | (255u - (e0 + 3))) : 0ull;

    // ---- 8 rounds of wave-wide argmax extraction (descending order, index tie-break) ----
    float sum = 0.f, myw = 0.f;
    int myid = 0;
    #pragma unroll
    for (int r = 0; r < TOPK; ++r) {
        uint64_t best = umax64(umax64(k0, k1), umax64(k2, k3));
        #pragma unroll
        for (int mask = 1; mask <= 32; mask <<= 1) {
            uint64_t o = (uint64_t)__shfl_xor((unsigned long long)best, mask, 64);
            best = umax64(best, o);
        }
        const uint32_t idx = 255u - (uint32_t)(best & 0xFFFFFFFFull);
        const int src  = (int)(idx >> 2);
        const int slot = (int)(idx & 3);
        // every lane selects the same slot, then broadcast the UNBIASED logit from owner lane
        float val = (slot == 0) ? v.x : (slot == 1) ? v.y : (slot == 2) ? v.z : v.w;
        float uv  = __shfl(val, src, 64);
        sum += uv;
        if (lane == r) { myw = uv; myid = (int)idx; }
        if (lane == src) {   // retire the winner
            if      (slot == 0) k0 = 0ull;
            else if (slot == 1) k1 = 0ull;
            else if (slot == 2) k2 = 0ull;
            else                k3 = 0ull;
        }
    }

    if (lane < TOPK) {
        out_w [(size_t)token * TOPK + lane] = myw / sum * RSF;
        out_id[(size_t)token * TOPK + lane] = (float)myid;
    }
}

extern "C" void kernel_launch(void* const* d_in, const int* in_sizes, int n_in,
                              void* d_out, int out_size, void* d_ws, size_t ws_size,
                              hipStream_t stream) {
    const float* logits = (const float*)d_in[0];
    const float* bias   = (const float*)d_in[1];
    const int T = in_sizes[0] / NEXP;   // 131072
    float* out = (float*)d_out;
    float* out_w  = out;
    float* out_id = out + (size_t)T * TOPK;

    const int waves_per_block = 256 / 64;
    const int blocks = (T + waves_per_block - 1) / waves_per_block;
    router_kernel<<<blocks, 256, 0, stream>>>(logits, bias, out_w, out_id, T);
}

// Round 2
// 257.607 us; speedup vs baseline: 1.1699x; 1.1699x over previous
//
#include <hip/hip_runtime.h>
#include <stdint.h>

static constexpr int TOPK   = 8;
static constexpr int NGROUP = 8;
static constexpr int TOPKG  = 4;
static constexpr int NEXP   = 256;
static constexpr float RSF  = 2.5f;

// DPP control codes (GCN/CDNA)
static constexpr int DPP_QUAD_XOR1   = 0xB1;  // quad_perm [1,0,3,2]
static constexpr int DPP_QUAD_XOR2   = 0x4E;  // quad_perm [2,3,0,1]
static constexpr int DPP_HALF_MIRROR = 0x141; // reverse within 8  (== xor4 once quads uniform)
static constexpr int DPP_MIRROR      = 0x140; // reverse within 16 (== xor8 once 8-groups uniform)
static constexpr int DPP_BCAST15     = 0x142; // lane15 -> next row
static constexpr int DPP_BCAST31     = 0x143; // lane31 -> rows 2,3

template <int CTRL>
__device__ __forceinline__ float dpp_f32(float x) {
    return __int_as_float(
        __builtin_amdgcn_update_dpp(0, __float_as_int(x), CTRL, 0xF, 0xF, true));
}

template <int CTRL>
__device__ __forceinline__ uint64_t dpp_u64(uint64_t x) {
    int lo = __builtin_amdgcn_update_dpp(0, (int)(uint32_t)x,         CTRL, 0xF, 0xF, true);
    int hi = __builtin_amdgcn_update_dpp(0, (int)(uint32_t)(x >> 32), CTRL, 0xF, 0xF, true);
    return ((uint64_t)(uint32_t)hi << 32) | (uint32_t)(uint32_t)lo;
}

__device__ __forceinline__ uint32_t f2sort(float f) {
    uint32_t u = __float_as_uint(f);
    return u ^ ((u & 0x80000000u) ? 0xFFFFFFFFu : 0x80000000u);
}

__device__ __forceinline__ uint64_t umax64(uint64_t a, uint64_t b) { return a > b ? a : b; }

__global__ __launch_bounds__(256) void router_kernel(
    const float* __restrict__ logits,   // [T, 256]
    const float* __restrict__ bias,     // [256]
    float* __restrict__ out_w,          // [T, 8]
    float* __restrict__ out_id,         // [T, 8] (ids as float)
    int T)
{
    const int lane  = threadIdx.x & 63;
    const int token = blockIdx.x * (blockDim.x >> 6) + (threadIdx.x >> 6);
    if (token >= T) return;

    // lane i owns experts 4i..4i+3 (within one 32-expert group, since 4 | 32)
    float4 v = ((const float4*)(logits + (size_t)token * NEXP))[lane];
    float4 b = ((const float4*)bias)[lane];

    const float s0 = v.x + b.x;
    const float s1 = v.y + b.y;
    const float s2 = v.z + b.z;
    const float s3 = v.w + b.w;

    // ---- group score: sum of top-2 biased scores per 8-lane (32-expert) group ----
    float hi01 = fmaxf(s0, s1), lo01 = fminf(s0, s1);
    float hi23 = fmaxf(s2, s3), lo23 = fminf(s2, s3);
    float m1 = fmaxf(hi01, hi23);
    float m2 = fmaxf(fminf(hi01, hi23), fmaxf(lo01, lo23));
    // merge sorted-2 lists across the 8-lane subgroup via DPP (xor1, xor2, xor4-equiv)
    {
        float o1 = dpp_f32<DPP_QUAD_XOR1>(m1), o2 = dpp_f32<DPP_QUAD_XOR1>(m2);
        float n1 = fmaxf(m1, o1);
        float n2 = fmaxf(fminf(m1, o1), fmaxf(m2, o2));
        m1 = n1; m2 = n2;
    }
    {
        float o1 = dpp_f32<DPP_QUAD_XOR2>(m1), o2 = dpp_f32<DPP_QUAD_XOR2>(m2);
        float n1 = fmaxf(m1, o1);
        float n2 = fmaxf(fminf(m1, o1), fmaxf(m2, o2));
        m1 = n1; m2 = n2;
    }
    {
        // quads uniform now, so half_mirror (xor7) delivers the xor4 partner's value
        float o1 = dpp_f32<DPP_HALF_MIRROR>(m1), o2 = dpp_f32<DPP_HALF_MIRROR>(m2);
        float n1 = fmaxf(m1, o1);
        float n2 = fmaxf(fminf(m1, o1), fmaxf(m2, o2));
        m1 = n1; m2 = n2;
    }
    const float gscore = m1 + m2;   // identical across the 8 lanes of each group

    // ---- top-4 groups; tie -> lower group index ----
    const int g = lane >> 3;
    int rank = 0;
    #pragma unroll
    for (int j = 0; j < NGROUP; ++j) {
        float gj = __int_as_float(
            __builtin_amdgcn_readlane(__float_as_int(gscore), j << 3));
        rank += ((gj > gscore) || (gj == gscore && j < g)) ? 1 : 0;
    }
    const bool sel = (rank < TOPKG);

    // ---- sortable keys: [f2sort(score) : (255 - expert_idx)]; masked -> 0 ----
    const uint32_t e0 = (uint32_t)(lane * 4);
    uint64_t k0 = sel ? (((uint64_t)f2sort(s0) << 32) | (255u - e0))       : 0ull;
    uint64_t k1 = sel ? (((uint64_t)f2sort(s1) << 32) | (255u - (e0 + 1))) : 0ull;
    uint64_t k2 = sel ? (((uint64_t)f2sort(s2) << 32) | (255u - (e0 + 2))) : 0ull;
    uint64_t k3 = sel ? (((uint64_t)f2sort(s3) << 32) | (255u - (e0 + 3))) : 0ull;

    // ---- 8 rounds of DPP wave-argmax (descending, index tie-break) ----
    float sum = 0.f, myw = 0.f;
    int myid = 0;
    #pragma unroll
    for (int r = 0; r < TOPK; ++r) {
        uint64_t best = umax64(umax64(k0, k1), umax64(k2, k3));
        best = umax64(best, dpp_u64<DPP_QUAD_XOR1>(best));
        best = umax64(best, dpp_u64<DPP_QUAD_XOR2>(best));
        best = umax64(best, dpp_u64<DPP_HALF_MIRROR>(best));
        best = umax64(best, dpp_u64<DPP_MIRROR>(best));
        // cross-row combine; valid result accumulates toward lane 63
        best = umax64(best, dpp_u64<DPP_BCAST15>(best));
        best = umax64(best, dpp_u64<DPP_BCAST31>(best));

        const uint32_t wlo = (uint32_t)__builtin_amdgcn_readlane((int)(uint32_t)best, 63);
        const uint32_t idx = 255u - wlo;        // scalar
        const int src  = (int)(idx >> 2);       // scalar
        const int slot = (int)(idx & 3);        // scalar

        // fetch the UNBIASED logit of the winner: 4 readlanes + scalar select
        float u0 = __int_as_float(__builtin_amdgcn_readlane(__float_as_int(v.x), src));
        float u1 = __int_as_float(__builtin_amdgcn_readlane(__float_as_int(v.y), src));
        float u2 = __int_as_float(__builtin_amdgcn_readlane(__float_as_int(v.z), src));
        float u3 = __int_as_float(__builtin_amdgcn_readlane(__float_as_int(v.w), src));
        float uv = (slot == 0) ? u0 : (slot == 1) ? u1 : (slot == 2) ? u2 : u3;

        sum += uv;
        if (lane == r) { myw = uv; myid = (int)idx; }

        if (lane == src) {   // retire the winner
            if      (slot == 0) k0 = 0ull;
            else if (slot == 1) k1 = 0ull;
            else if (slot == 2) k2 = 0ull;
            else                k3 = 0ull;
        }
    }

    if (lane < TOPK) {
        out_w [(size_t)token * TOPK + lane] = myw / sum * RSF;
        out_id[(size_t)token * TOPK + lane] = (float)myid;
    }
}

extern "C" void kernel_launch(void* const* d_in, const int* in_sizes, int n_in,
                              void* d_out, int out_size, void* d_ws, size_t ws_size,
                              hipStream_t stream) {
    const float* logits = (const float*)d_in[0];
    const float* bias   = (const float*)d_in[1];
    const int T = in_sizes[0] / NEXP;   // 131072
    float* out = (float*)d_out;
    float* out_w  = out;
    float* out_id = out + (size_t)T * TOPK;

    const int waves_per_block = 256 / 64;
    const int blocks = (T + waves_per_block - 1) / waves_per_block;
    router_kernel<<<blocks, 256, 0, stream>>>(logits, bias, out_w, out_id, T);
}

// Round 4
// 239.844 us; speedup vs baseline: 1.2566x; 1.0741x over previous
//
#include <hip/hip_runtime.h>
#include <stdint.h>
#include <math.h>

static constexpr int TOPK   = 8;
static constexpr int NGROUP = 8;
static constexpr int TOPKG  = 4;
static constexpr int NEXP   = 256;
static constexpr float RSF  = 2.5f;

// DPP control codes
static constexpr int DPP_QX1 = 0xB1;  // quad_perm [1,0,3,2]  == xor1
static constexpr int DPP_QX2 = 0x4E;  // quad_perm [2,3,0,1]  == xor2
static constexpr int DPP_HM  = 0x141; // row_half_mirror      == xor4 once quads uniform
static constexpr int DPP_MIR = 0x140; // row_mirror           == xor8 once 8-blocks uniform
static constexpr int DPP_B15 = 0x142; // row_bcast15
static constexpr int DPP_B31 = 0x143; // row_bcast31

// old = src so lanes the pattern doesn't write keep their own value
// (safe for max/add; bcast15/31 leave low lanes unwritten)
template <int CTRL>
__device__ __forceinline__ float dppmov(float x) {
    int xi = __float_as_int(x);
    return __int_as_float(__builtin_amdgcn_update_dpp(xi, xi, CTRL, 0xF, 0xF, false));
}

__device__ __forceinline__ uint32_t f2sort(float f) {
    uint32_t u = __float_as_uint(f);
    return u ^ ((uint32_t)((int32_t)u >> 31) | 0x80000000u);
}

__global__ __launch_bounds__(256) void router_kernel(
    const float* __restrict__ logits,   // [T, 256]
    const float* __restrict__ bias,     // [256]
    float* __restrict__ out_w,          // [T, 8]
    float* __restrict__ out_id,         // [T, 8] (ids as float)
    int T)
{
    const int lane  = threadIdx.x & 63;
    const int token = blockIdx.x * (blockDim.x >> 6) + (threadIdx.x >> 6);
    if (token >= T) return;

    const float* row = logits + (size_t)token * NEXP;
    float4 v = ((const float4*)row)[lane];
    float4 b = ((const float4*)bias)[lane];

    const float s0 = v.x + b.x;
    const float s1 = v.y + b.y;
    const float s2 = v.z + b.z;
    const float s3 = v.w + b.w;

    // ---- group score: sum of top-2 biased scores per 8-lane (32-expert) group ----
    float hi01 = fmaxf(s0, s1), lo01 = fminf(s0, s1);
    float hi23 = fmaxf(s2, s3), lo23 = fminf(s2, s3);
    float m1 = fmaxf(hi01, hi23);
    float m2 = fmaxf(fminf(hi01, hi23), fmaxf(lo01, lo23));
    {   // merge sorted pairs across xor1, xor2, xor4(half-mirror)
        float o1 = dppmov<DPP_QX1>(m1), o2 = dppmov<DPP_QX1>(m2);
        float n1 = fmaxf(m1, o1);
        float n2 = fmaxf(fminf(m1, o1), fmaxf(m2, o2));
        m1 = n1; m2 = n2;
    }
    {
        float o1 = dppmov<DPP_QX2>(m1), o2 = dppmov<DPP_QX2>(m2);
        float n1 = fmaxf(m1, o1);
        float n2 = fmaxf(fminf(m1, o1), fmaxf(m2, o2));
        m1 = n1; m2 = n2;
    }
    {
        float o1 = dppmov<DPP_HM>(m1), o2 = dppmov<DPP_HM>(m2);
        float n1 = fmaxf(m1, o1);
        float n2 = fmaxf(fminf(m1, o1), fmaxf(m2, o2));
        m1 = n1; m2 = n2;
    }
    const float gscore = m1 + m2;   // uniform within each 8-lane group

    // ---- top-4 groups, exact tie-break (lower group index) via u64 group key ----
    const int g = lane >> 3;
    const uint64_t gkey = ((uint64_t)f2sort(gscore) << 32) | (uint32_t)(7 - g);
    int rank = 0;
    #pragma unroll
    for (int j = 0; j < NGROUP; ++j) {
        uint32_t hi = (uint32_t)__builtin_amdgcn_readlane((int)(uint32_t)(gkey >> 32), j << 3);
        uint32_t lo = (uint32_t)__builtin_amdgcn_readlane((int)(uint32_t)gkey,         j << 3);
        uint64_t gj = ((uint64_t)hi << 32) | lo;
        rank += (gj > gkey) ? 1 : 0;
    }
    const bool sel = (rank < TOPKG);

    // ---- current biased scores, masked to -inf outside selected groups ----
    const float NEG = -INFINITY;
    float c0 = sel ? s0 : NEG;
    float c1 = sel ? s1 : NEG;
    float c2 = sel ? s2 : NEG;
    float c3 = sel ? s3 : NEG;
    const int ebase = lane << 2;   // expert index of slot 0

    int myid = 0;
    #pragma unroll
    for (int r = 0; r < TOPK; ++r) {
        // wave max (f32), accumulating toward lane 63
        float x = fmaxf(fmaxf(c0, c1), fmaxf(c2, c3));
        x = fmaxf(x, dppmov<DPP_QX1>(x));
        x = fmaxf(x, dppmov<DPP_QX2>(x));
        x = fmaxf(x, dppmov<DPP_HM >(x));
        x = fmaxf(x, dppmov<DPP_MIR>(x));
        x = fmaxf(x, dppmov<DPP_B15>(x));
        x = fmaxf(x, dppmov<DPP_B31>(x));
        const float smax = __int_as_float(
            __builtin_amdgcn_readlane(__float_as_int(x), 63));   // scalar

        // lane-local lowest slot matching smax; wave-lowest lane via ballot
        int slot = (c0 == smax) ? 0 : (c1 == smax) ? 1 : (c2 == smax) ? 2 : 3;
        int lidx = ebase | slot;
        uint64_t bal = __ballot((c0 == smax) || (c1 == smax) ||
                                (c2 == smax) || (c3 == smax));
        const int wlane = __ffsll((unsigned long long)bal) - 1;   // scalar, lowest lane
        const int idx   = __builtin_amdgcn_readlane(lidx, wlane); // scalar expert id

        // record: idx and r are wave-uniform, so a cndmask replaces writelane
        myid = (lane == r) ? idx : myid;

        // retire exactly that expert (branch-free)
        c0 = (ebase == idx    ) ? NEG : c0;
        c1 = (ebase == idx - 1) ? NEG : c1;
        c2 = (ebase == idx - 2) ? NEG : c2;
        c3 = (ebase == idx - 3) ? NEG : c3;
    }

    // ---- gather unbiased logits for lanes 0..7, reduce sum over the 8 ----
    float w = 0.f;
    if (lane < TOPK) w = row[myid];        // L1-hot: row was just loaded
    float t = w;
    t += dppmov<DPP_QX1>(t);
    t += dppmov<DPP_QX2>(t);
    t += dppmov<DPP_HM >(t);               // lanes 0..7 now all hold the 8-sum

    if (lane < TOPK) {
        out_w [(size_t)token * TOPK + lane] = w / t * RSF;
        out_id[(size_t)token * TOPK + lane] = (float)myid;
    }
}

extern "C" void kernel_launch(void* const* d_in, const int* in_sizes, int n_in,
                              void* d_out, int out_size, void* d_ws, size_t ws_size,
                              hipStream_t stream) {
    const float* logits = (const float*)d_in[0];
    const float* bias   = (const float*)d_in[1];
    const int T = in_sizes[0] / NEXP;   // 131072
    float* out = (float*)d_out;
    float* out_w  = out;
    float* out_id = out + (size_t)T * TOPK;

    const int waves_per_block = 256 / 64;
    const int blocks = (T + waves_per_block - 1) / waves_per_block;
    router_kernel<<<blocks, 256, 0, stream>>>(logits, bias, out_w, out_id, T);
}

// Round 5
// 218.547 us; speedup vs baseline: 1.3790x; 1.0974x over previous
//
#include <hip/hip_runtime.h>
#include <stdint.h>
#include <math.h>

static constexpr int TOPK   = 8;
static constexpr int TOPKG  = 4;
static constexpr int NEXP   = 256;
static constexpr float RSF  = 2.5f;

// DPP control codes
static constexpr int DPP_QX1 = 0xB1;  // quad_perm [1,0,3,2]  == xor1
static constexpr int DPP_QX2 = 0x4E;  // quad_perm [2,3,0,1]  == xor2
static constexpr int DPP_HM  = 0x141; // row_half_mirror      == xor4 once quads uniform
static constexpr int DPP_MIR = 0x140; // row_mirror           == xor8 once 8-blocks uniform
static constexpr int DPP_B15 = 0x142; // row_bcast15
static constexpr int DPP_B31 = 0x143; // row_bcast31

// old = src so unwritten lanes keep their own value (safe for max/add trees)
template <int CTRL>
__device__ __forceinline__ float dppmov(float x) {
    int xi = __float_as_int(x);
    return __int_as_float(__builtin_amdgcn_update_dpp(xi, xi, CTRL, 0xF, 0xF, false));
}

// descending compare-exchange with index payload
__device__ __forceinline__ void cas(float& ax, float& ay, int& ix, int& iy) {
    bool p   = ax < ay;
    float hi = fmaxf(ax, ay), lo = fminf(ax, ay);
    int   nx = p ? iy : ix,   ny = p ? ix : iy;
    ax = hi; ay = lo; ix = nx; iy = ny;
}

__global__ __launch_bounds__(256) void router_kernel(
    const float* __restrict__ logits,   // [T, 256]
    const float* __restrict__ bias,     // [256]
    float* __restrict__ out_w,          // [T, 8]
    float* __restrict__ out_id,         // [T, 8] (ids as float)
    int T)
{
    const int lane  = threadIdx.x & 63;
    const int token = blockIdx.x * (blockDim.x >> 6) + (threadIdx.x >> 6);
    if (token >= T) return;

    const float* row = logits + (size_t)token * NEXP;
    float4 v = ((const float4*)row)[lane];
    float4 b = ((const float4*)bias)[lane];

    float s0 = v.x + b.x;
    float s1 = v.y + b.y;
    float s2 = v.z + b.z;
    float s3 = v.w + b.w;

    // ---- group score: sum of top-2 biased scores per 8-lane (32-expert) group ----
    float hi01 = fmaxf(s0, s1), lo01 = fminf(s0, s1);
    float hi23 = fmaxf(s2, s3), lo23 = fminf(s2, s3);
    float m1 = fmaxf(hi01, hi23);
    float m2 = fmaxf(fminf(hi01, hi23), fmaxf(lo01, lo23));
    {
        float o1 = dppmov<DPP_QX1>(m1), o2 = dppmov<DPP_QX1>(m2);
        float n1 = fmaxf(m1, o1);
        float n2 = fmaxf(fminf(m1, o1), fmaxf(m2, o2));
        m1 = n1; m2 = n2;
    }
    {
        float o1 = dppmov<DPP_QX2>(m1), o2 = dppmov<DPP_QX2>(m2);
        float n1 = fmaxf(m1, o1);
        float n2 = fmaxf(fminf(m1, o1), fmaxf(m2, o2));
        m1 = n1; m2 = n2;
    }
    {
        float o1 = dppmov<DPP_HM>(m1), o2 = dppmov<DPP_HM>(m2);
        float n1 = fmaxf(m1, o1);
        float n2 = fmaxf(fminf(m1, o1), fmaxf(m2, o2));
        m1 = n1; m2 = n2;
    }
    const float gscore = m1 + m2;   // uniform within each 8-lane group

    // ---- group rank via one shuffle-transpose + ballot + byte popcount ----
    // lane sees group (lane&7)'s score; exact (value desc, index asc) predicate
    const int g = lane >> 3;
    const int j = lane & 7;
    float gj = __shfl(gscore, j << 3, 64);
    bool beats = (gj > gscore) || (gj == gscore && j < g);
    uint64_t bal = __ballot(beats);
    int rank = __popcll(bal & (0xFFull << (g << 3)));
    const bool sel = (rank < TOPKG);

    // ---- mask to -inf outside selected groups; sort lane's 4 (val,idx) desc ----
    const float NEG = -INFINITY;
    float a0 = sel ? s0 : NEG;
    float a1 = sel ? s1 : NEG;
    float a2 = sel ? s2 : NEG;
    float a3 = sel ? s3 : NEG;
    const int ebase = lane << 2;
    int i0 = ebase, i1 = ebase + 1, i2 = ebase + 2, i3 = ebase + 3;
    cas(a0, a1, i0, i1);
    cas(a2, a3, i2, i3);
    cas(a0, a2, i0, i2);
    cas(a1, a3, i1, i3);
    cas(a1, a2, i1, i2);
    uint32_t ipack = (uint32_t)i0 | ((uint32_t)i1 << 8) |
                     ((uint32_t)i2 << 16) | ((uint32_t)i3 << 24);
    int i0cur = i0;

    int   myid = 0;
    float myw  = 0.f;
    #pragma unroll
    for (int r = 0; r < TOPK; ++r) {
        // wave max of heads (a0), accumulating toward lane 63
        float x = a0;
        x = fmaxf(x, dppmov<DPP_QX1>(x));
        x = fmaxf(x, dppmov<DPP_QX2>(x));
        x = fmaxf(x, dppmov<DPP_HM >(x));
        x = fmaxf(x, dppmov<DPP_MIR>(x));
        x = fmaxf(x, dppmov<DPP_B15>(x));
        x = fmaxf(x, dppmov<DPP_B31>(x));
        const float smax = __int_as_float(
            __builtin_amdgcn_readlane(__float_as_int(x), 63));      // scalar

        uint64_t wb  = __ballot(a0 == smax);                        // single v_cmp
        const int wl = __ffsll((unsigned long long)wb) - 1;         // scalar lane
        const int idx = __builtin_amdgcn_readlane(i0cur, wl);       // scalar expert id

        // record (idx, smax uniform; one cmp serves both cndmasks)
        const bool mine = (lane == r);
        myid = mine ? idx  : myid;
        myw  = mine ? smax : myw;

        // winner lane shifts its sorted list up
        const bool win = (lane == wl);
        a0 = win ? a1  : a0;
        a1 = win ? a2  : a1;
        a2 = win ? a3  : a2;
        a3 = win ? NEG : a3;
        ipack = win ? (ipack >> 8) : ipack;
        i0cur = (int)(ipack & 255u);   // for next round's readlane (no hazard)
    }

    // ---- unbias: myw holds biased score; subtract bias[myid] (L1-hot) ----
    float bi = 0.f;
    if (lane < TOPK) bi = bias[myid];
    float w = myw - bi;                       // lanes >= 8: 0 - 0 = 0

    // sum across the 8 result lanes (lanes 0..7 form one 8-group)
    float t = w;
    t += dppmov<DPP_QX1>(t);
    t += dppmov<DPP_QX2>(t);
    t += dppmov<DPP_HM >(t);

    if (lane < TOPK) {
        out_w [(size_t)token * TOPK + lane] = w / t * RSF;
        out_id[(size_t)token * TOPK + lane] = (float)myid;
    }
}

extern "C" void kernel_launch(void* const* d_in, const int* in_sizes, int n_in,
                              void* d_out, int out_size, void* d_ws, size_t ws_size,
                              hipStream_t stream) {
    const float* logits = (const float*)d_in[0];
    const float* bias   = (const float*)d_in[1];
    const int T = in_sizes[0] / NEXP;   // 131072
    float* out = (float*)d_out;
    float* out_w  = out;
    float* out_id = out + (size_t)T * TOPK;

    const int waves_per_block = 256 / 64;
    const int blocks = (T + waves_per_block - 1) / waves_per_block;
    router_kernel<<<blocks, 256, 0, stream>>>(logits, bias, out_w, out_id, T);
}